// Round 7
// baseline (431.909 us; speedup 1.0000x reference)
//
#include <hip/hip_runtime.h>

// BMM_S8T_S8N_F16T: out[b,m,n] = fp16-range(alpha * sum_k A[b,m,k]*B[b,n,k])
// A: (B,M,K) int32 (int8-range), B: (B,N,K) int32, out: float. B=64, M=N=1024, K=128.
//
// Roofline: 268 MB write + 67 MB read => ~53 us @6.3 TB/s. Write-dominated.
// Ledger: R6 barriers / R8 store macro-pattern / R10 store throughput (+268MB
//   dup = only +24us) / R11 occupancy (2 blk/CU REGRESSED -20us) all
//   exonerated. Kernel inferred ~140-160us vs 53 roofline, but its counters
//   have NEVER been observed (always below top-5 fills). Three live theories:
//   (a) write-amp via RFO (would show FETCH ~300+MB), (b) B-reuse L2 thrash
//   (FETCH 150-250MB), (c) no amp at all -> true kernel fast, baseline is
//   fill+overhead (dur-100 <= 80us).
// R12 = CALIBRATED VISIBILITY PROBE: R9 verbatim (best, 330.6us) + fixed
//   100us wall-clock spin (s_memrealtime, 100MHz, throttle-independent)
//   AFTER all stores are issued. Traffic untouched & drains during spin ->
//   kernel's real FETCH_SIZE/WRITE_SIZE become top-1 visible, and
//   dur(kernel) - 100us = first direct true-kernel-time measurement.

#define Mdim 1024
#define Ndim 1024
#define Kdim 128
#define NROWS 16     // m-rows per strip
#define NSTRIPS 16   // strips per block -> 256 m-rows
#define BSTRIDE 128  // packed bytes per B row (no pad; XOR swizzle instead)

using int32x4 = __attribute__((ext_vector_type(4))) int;
using floatx4 = __attribute__((ext_vector_type(4))) float;

__device__ __forceinline__ unsigned pack8(int32x4 v) {
    return (unsigned)(v.x & 255) | ((unsigned)(v.y & 255) << 8)
         | ((unsigned)(v.z & 255) << 16) | ((unsigned)(v.w & 255) << 24);
}

// B-tile swizzle: XOR row&7 into the 16-B-unit bits (bijective per row).
__device__ __forceinline__ int swz(int byte_off) {
    return byte_off ^ (((byte_off >> 7) & 7) << 4);
}

// LDS-only barrier: no vmcnt drain -> in-flight global stores keep streaming.
__device__ __forceinline__ void lds_barrier() {
    asm volatile("s_waitcnt lgkmcnt(0)\n\ts_barrier" ::: "memory");
}

__global__ __launch_bounds__(512, 2)
void bmm_s8_kernel(const int* __restrict__ A, const int* __restrict__ Bm,
                   const float* __restrict__ alpha_p, float* __restrict__ out)
{
    __shared__ unsigned char Bs[1024 * BSTRIDE];  // 128 KiB: full B, packed int8
    __shared__ int32x4 Cs4[1024];                 // 16 KiB: 4-row f32 chunk (transpose buf)
    unsigned char* const Cs = (unsigned char*)Cs4;

    const int t    = threadIdx.x;
    const int z    = blockIdx.x;   // batch; linear%8 == z%8 -> per-XCD batch affinity
    const int q    = blockIdx.y;   // m-quarter: rows [q*256, q*256+256)
    const int lane = t & 63;
    const int wave = t >> 6;       // 0..7
    const int wn   = wave * 128;   // this wave's n band

    const int* __restrict__ Ab = A  + (size_t)z * Mdim * Kdim + (size_t)(q * 256) * Kdim;
    const int* __restrict__ Bb = Bm + (size_t)z * Ndim * Kdim;
    float* __restrict__ Ob     = out + (size_t)z * Mdim * Ndim + (size_t)(q * 256) * Ndim;

    const int r = lane & 15;   // fragment m-row within 16, also D col owner
    const int g = lane >> 4;   // fragment k-chunk selector, also D 4-col group

    // ---- issue A prefetch for strip 0 (oldest loads; land during staging) ----
    int32x4 araw[8];
#pragma unroll
    for (int k = 0; k < 8; ++k) {
        const int ks = k >> 2, i = k & 3;
        araw[k] = *(const int32x4*)(Ab + (size_t)r * Kdim + ks * 64 + g * 16 + i * 4);
    }

    // ---- stage FULL B (1024 rows x 32 16-B chunks = 32768 chunks) ----
#pragma unroll 1
    for (int rr = 0; rr < 4; ++rr) {
        int32x4 breg[16];
#pragma unroll
        for (int j = 0; j < 16; ++j) {
            const int f    = t + 512 * (rr * 16 + j);
            const int row  = f >> 5;
            const int colb = (f & 31) * 4;
            breg[j] = *(const int32x4*)(Bb + (size_t)row * Kdim + colb);
        }
#pragma unroll
        for (int j = 0; j < 16; ++j) {
            const int f    = t + 512 * (rr * 16 + j);
            const int row  = f >> 5;
            const int colb = (f & 31) * 4;
            *(unsigned*)(&Bs[swz(row * BSTRIDE + colb)]) = pack8(breg[j]);
        }
    }
    __syncthreads();

    const float alpha = alpha_p[0];

#pragma unroll 1
    for (int s = 0; s < NSTRIPS; ++s) {
        // consume prefetched A into fragments
        int32x4 af[2];
#pragma unroll
        for (int ks = 0; ks < 2; ++ks)
            af[ks] = (int32x4){ (int)pack8(araw[ks * 4 + 0]), (int)pack8(araw[ks * 4 + 1]),
                                (int)pack8(araw[ks * 4 + 2]), (int)pack8(araw[ks * 4 + 3]) };

        // issue next strip's A loads (in flight across compute + stores)
        if (s + 1 < NSTRIPS) {
            const int* __restrict__ An = Ab + (size_t)((s + 1) * NROWS) * Kdim;
#pragma unroll
            for (int k = 0; k < 8; ++k) {
                const int ks = k >> 2, i = k & 3;
                araw[k] = *(const int32x4*)(An + (size_t)r * Kdim + ks * 64 + g * 16 + i * 4);
            }
        }

        // ---- MFMA: wave computes 16(m) x 128(n) of this strip ----
        int32x4 acc[8];
#pragma unroll
        for (int nt = 0; nt < 8; ++nt)
            acc[nt] = (int32x4){0, 0, 0, 0};

#pragma unroll
        for (int ks = 0; ks < 2; ++ks) {
#pragma unroll
            for (int nt = 0; nt < 8; ++nt) {
                const int row = wn + nt * 16 + r;
                int32x4 bf = *(const int32x4*)(&Bs[swz(row * BSTRIDE + ks * 64 + g * 16)]);
                acc[nt] = __builtin_amdgcn_mfma_i32_16x16x64_i8(bf, af[ks], acc[nt], 0, 0, 0);
            }
        }

        // convert once: lane holds out[m=r][n = wn + nt*16 + g*4 + j]
        floatx4 facc[8];
#pragma unroll
        for (int nt = 0; nt < 8; ++nt) {
            facc[nt].x = alpha * (float)acc[nt][0];
            facc[nt].y = alpha * (float)acc[nt][1];
            facc[nt].z = alpha * (float)acc[nt][2];
            facc[nt].w = alpha * (float)acc[nt][3];
        }

        // ---- epilogue: 4 chunks of 4 rows; transpose via LDS, store as
        //      1-KB-contiguous-per-instruction nontemporal full-line writes ----
#pragma unroll
        for (int c = 0; c < 4; ++c) {
            if ((r >> 2) == c) {
                const int rowL = r & 3;
                const int xo   = (rowL & 3) << 4;
#pragma unroll
                for (int nt = 0; nt < 8; ++nt) {
                    const int off = rowL * 4096 + wn * 4 + nt * 64 + g * 16;
                    *(floatx4*)(&Cs[off ^ xo]) = facc[nt];
                }
            }
            lds_barrier();  // chunk data visible; stores below never drained here

            const size_t basef = (size_t)(s * NROWS + c * 4) * Ndim;  // float index
#pragma unroll
            for (int p = 0; p < 2; ++p) {
                const int off  = (t + p * 512) * 16;       // byte offset in 16-KB chunk
                const int rowL = off >> 12;
                floatx4 v = *(const floatx4*)(&Cs[off ^ ((rowL & 3) << 4)]);
                __builtin_nontemporal_store(v, (floatx4*)(Ob + basef + (off >> 2)));
            }

            lds_barrier();  // reads done before next chunk overwrites Cs
        }
    }

    // ---- PROBE: fixed 100 us wall-clock spin (s_memrealtime = 100 MHz,
    //      throttle-independent). All traffic above drains during the spin,
    //      so this dispatch's FETCH_SIZE/WRITE_SIZE are the kernel's real
    //      traffic, and dur(kernel) - 100us = true kernel time. ----
    {
        const unsigned long long t0 = __builtin_amdgcn_s_memrealtime();
        while (__builtin_amdgcn_s_memrealtime() - t0 < 10000ULL) {
            asm volatile("s_nop 0" ::: "memory");
        }
    }
}

extern "C" void kernel_launch(void* const* d_in, const int* in_sizes, int n_in,
                              void* d_out, int out_size, void* d_ws, size_t ws_size,
                              hipStream_t stream) {
    const int*   a     = (const int*)d_in[0];
    const int*   b     = (const int*)d_in[1];
    const float* alpha = (const float*)d_in[2];
    float*       out   = (float*)d_out;

    const int batch = in_sizes[0] / (Mdim * Kdim);  // 64
    dim3 grid(batch, Mdim / (NROWS * NSTRIPS));     // (64, 4): 256 blocks = 1/CU
    bmm_s8_kernel<<<grid, 512, 0, stream>>>(a, b, alpha, out);
}

// Round 8
// 322.963 us; speedup vs baseline: 1.3373x; 1.3373x over previous
//
#include <hip/hip_runtime.h>

// BMM_S8T_S8N_F16T: out[b,m,n] = fp16-range(alpha * sum_k A[b,m,k]*B[b,n,k])
// A: (B,M,K) int32 (int8-range), B: (B,N,K) int32, out: float. B=64, M=N=1024, K=128.
//
// R12 PROBE RESULTS (first real counters): true kernel = ~97 us (197 - 100us
//   spin); harness fixed overhead ~233 us. WRITE_SIZE = 268 MB EXACT (no
//   write amp), FETCH = 33 MB (< inputs; L3 serves B reuse; no read amp).
//   Occupancy 23% (8 waves), MfmaUtil ~3%, VALUBusy ~19% of active window.
//   => Issue-side bound: 128 block-wide lds_barriers pacing 64 tiny chunk
//   phases + serial stage account for the ~45 us above the 46 us store floor.
// R13: ZERO in-loop barriers. C-transpose buffer made WAVE-PRIVATE (2 KB per
//   wave, 4-row sub-chunks, double-use gated by same-wave lgkmcnt(0) only).
//   Stores: 2x 512-B contiguous segments per instruction (full 128-B lines
//   preserved -- the R9>R8 property). 8 wave streams free-run per CU; one
//   wave's stores overlap others' MFMA/LDS. Stage/A-prefetch/MFMA: R9
//   verbatim. LDS 147456 B (known-good size).

#define Mdim 1024
#define Ndim 1024
#define Kdim 128
#define NROWS 16     // m-rows per strip
#define NSTRIPS 16   // strips per block -> 256 m-rows
#define BSTRIDE 128  // packed bytes per B row (no pad; XOR swizzle instead)
#define WAVEBUF 2048 // per-wave transpose buffer (4 rows x 512 B)

using int32x4 = __attribute__((ext_vector_type(4))) int;
using floatx4 = __attribute__((ext_vector_type(4))) float;

__device__ __forceinline__ unsigned pack8(int32x4 v) {
    return (unsigned)(v.x & 255) | ((unsigned)(v.y & 255) << 8)
         | ((unsigned)(v.z & 255) << 16) | ((unsigned)(v.w & 255) << 24);
}

// B-tile swizzle: XOR row&7 into the 16-B-unit bits (bijective per row).
__device__ __forceinline__ int swz(int byte_off) {
    return byte_off ^ (((byte_off >> 7) & 7) << 4);
}

// Same-wave LDS drain (no barrier, no vmcnt): orders ds_write -> ds_read
// within the wave. sched_barrier keeps the compiler from hoisting the
// dependent LDS ops across the wait (guide rule #18).
__device__ __forceinline__ void wave_lds_fence() {
    asm volatile("s_waitcnt lgkmcnt(0)" ::: "memory");
    __builtin_amdgcn_sched_barrier(0);
}

__global__ __launch_bounds__(512, 2)
void bmm_s8_kernel(const int* __restrict__ A, const int* __restrict__ Bm,
                   const float* __restrict__ alpha_p, float* __restrict__ out)
{
    __shared__ unsigned char Bs[1024 * BSTRIDE];  // 128 KiB: full B, packed int8
    __shared__ unsigned char Ws[8 * WAVEBUF];     // 16 KiB: wave-private transpose bufs

    const int t    = threadIdx.x;
    const int z    = blockIdx.x;   // batch; linear%8 == z%8 -> per-XCD batch affinity
    const int q    = blockIdx.y;   // m-quarter: rows [q*256, q*256+256)
    const int lane = t & 63;
    const int wave = t >> 6;       // 0..7
    const int wn   = wave * 128;   // this wave's n band

    const int* __restrict__ Ab = A  + (size_t)z * Mdim * Kdim + (size_t)(q * 256) * Kdim;
    const int* __restrict__ Bb = Bm + (size_t)z * Ndim * Kdim;
    float* __restrict__ Ob     = out + (size_t)z * Mdim * Ndim + (size_t)(q * 256) * Ndim;

    const int r = lane & 15;   // fragment m-row within 16
    const int g = lane >> 4;   // fragment k-chunk selector / 4-col group

    // ---- issue A prefetch for strip 0 (oldest loads; land during staging) ----
    int32x4 araw[8];
#pragma unroll
    for (int k = 0; k < 8; ++k) {
        const int ks = k >> 2, i = k & 3;
        araw[k] = *(const int32x4*)(Ab + (size_t)r * Kdim + ks * 64 + g * 16 + i * 4);
    }

    // ---- stage FULL B (1024 rows x 32 16-B chunks = 32768 chunks) ----
#pragma unroll 1
    for (int rr = 0; rr < 4; ++rr) {
        int32x4 breg[16];
#pragma unroll
        for (int j = 0; j < 16; ++j) {
            const int f    = t + 512 * (rr * 16 + j);
            const int row  = f >> 5;
            const int colb = (f & 31) * 4;
            breg[j] = *(const int32x4*)(Bb + (size_t)row * Kdim + colb);
        }
#pragma unroll
        for (int j = 0; j < 16; ++j) {
            const int f    = t + 512 * (rr * 16 + j);
            const int row  = f >> 5;
            const int colb = (f & 31) * 4;
            *(unsigned*)(&Bs[swz(row * BSTRIDE + colb)]) = pack8(breg[j]);
        }
    }
    __syncthreads();  // the ONLY block-wide barrier in the kernel

    const float alpha = alpha_p[0];
    unsigned char* const Wb = &Ws[wave * WAVEBUF];

#pragma unroll 1
    for (int s = 0; s < NSTRIPS; ++s) {
        // consume prefetched A into fragments
        int32x4 af[2];
#pragma unroll
        for (int ks = 0; ks < 2; ++ks)
            af[ks] = (int32x4){ (int)pack8(araw[ks * 4 + 0]), (int)pack8(araw[ks * 4 + 1]),
                                (int)pack8(araw[ks * 4 + 2]), (int)pack8(araw[ks * 4 + 3]) };

        // issue next strip's A loads (in flight across compute + stores)
        if (s + 1 < NSTRIPS) {
            const int* __restrict__ An = Ab + (size_t)((s + 1) * NROWS) * Kdim;
#pragma unroll
            for (int k = 0; k < 8; ++k) {
                const int ks = k >> 2, i = k & 3;
                araw[k] = *(const int32x4*)(An + (size_t)r * Kdim + ks * 64 + g * 16 + i * 4);
            }
        }

        // ---- MFMA: wave computes 16(m) x 128(n) of this strip ----
        int32x4 acc[8];
#pragma unroll
        for (int nt = 0; nt < 8; ++nt)
            acc[nt] = (int32x4){0, 0, 0, 0};

#pragma unroll
        for (int ks = 0; ks < 2; ++ks) {
#pragma unroll
            for (int nt = 0; nt < 8; ++nt) {
                const int row = wn + nt * 16 + r;
                int32x4 bf = *(const int32x4*)(&Bs[swz(row * BSTRIDE + ks * 64 + g * 16)]);
                // swapped operands: D cols = m (lane&15), regs = 4 consecutive n
                acc[nt] = __builtin_amdgcn_mfma_i32_16x16x64_i8(bf, af[ks], acc[nt], 0, 0, 0);
            }
        }

        // convert once: lane holds out[m = r][n = wn + nt*16 + g*4 + 0..3]
        floatx4 facc[8];
#pragma unroll
        for (int nt = 0; nt < 8; ++nt) {
            facc[nt].x = alpha * (float)acc[nt][0];
            facc[nt].y = alpha * (float)acc[nt][1];
            facc[nt].z = alpha * (float)acc[nt][2];
            facc[nt].w = alpha * (float)acc[nt][3];
        }

        // ---- epilogue: wave-private transpose, ZERO barriers.
        //      4 sub-chunks of 4 m-rows x 128 n (2 KB each). Lanes with
        //      r>>2==c write their whole row-segment; same-wave lgkmcnt
        //      fences; all 64 lanes read + nt-store two 512-B full-line
        //      segments per instruction. ----
#pragma unroll
        for (int c = 0; c < 4; ++c) {
            // previous sub-chunk's reads must be done before overwriting Wb
            wave_lds_fence();
            if ((r >> 2) == c) {
                const int rl = r & 3;
#pragma unroll
                for (int nt = 0; nt < 8; ++nt) {
                    const int inrow = nt * 64 + g * 16;       // byte off within 512-B row
                    *(floatx4*)(&Wb[rl * 512 + (inrow ^ (rl << 4))]) = facc[nt];
                }
            }
            wave_lds_fence();  // writes visible to all lanes of this wave
#pragma unroll
            for (int p = 0; p < 2; ++p) {
                const int rowL  = p * 2 + (lane >> 5);        // 0..3
                const int inrow = (lane & 31) * 16;
                floatx4 v = *(const floatx4*)(&Wb[rowL * 512 + (inrow ^ (rowL << 4))]);
                const size_t fidx = (size_t)(s * NROWS + c * 4 + rowL) * Ndim
                                  + wn + (lane & 31) * 4;
                __builtin_nontemporal_store(v, (floatx4*)(Ob + fidx));
            }
        }
    }
}

extern "C" void kernel_launch(void* const* d_in, const int* in_sizes, int n_in,
                              void* d_out, int out_size, void* d_ws, size_t ws_size,
                              hipStream_t stream) {
    const int*   a     = (const int*)d_in[0];
    const int*   b     = (const int*)d_in[1];
    const float* alpha = (const float*)d_in[2];
    float*       out   = (float*)d_out;

    const int batch = in_sizes[0] / (Mdim * Kdim);  // 64
    dim3 grid(batch, Mdim / (NROWS * NSTRIPS));     // (64, 4): 256 blocks = 1/CU
    bmm_s8_kernel<<<grid, 512, 0, stream>>>(a, b, alpha, out);
}